// Round 1
// baseline (149.558 us; speedup 1.0000x reference)
//
#include <hip/hip_runtime.h>

// Majority filter, 3x3, replicate padding, 8 label bins, ties -> smallest label.
// Run exactly 8 iterations (idempotent at fixed point == early-stop semantics).
//
// Histogram trick: labels in [0,8) -> one u64, one byte per bin (max count 9).
// hist = sum over 9 neighbors of (1ull << (8*label)); argmax scans bytes with
// strict > so the FIRST maximum (smallest label) wins, matching jnp.argmax.

__device__ __forceinline__ int argmax_hist8(unsigned long long h) {
    int best = 0;
    unsigned int bc = (unsigned int)(h & 0xffull);
#pragma unroll
    for (int i = 1; i < 8; ++i) {
        unsigned int c = (unsigned int)((h >> (8 * i)) & 0xffull);
        if (c > bc) { bc = c; best = i; }
    }
    return best;
}

template <typename Tin, typename Tout>
__global__ __launch_bounds__(256) void majority_iter_kernel(
    const Tin* __restrict__ in, Tout* __restrict__ out,
    int H, int W, int total) {
    int idx = blockIdx.x * blockDim.x + threadIdx.x;
    if (idx >= total) return;

    int x = idx % W;
    int rest = idx / W;
    int y = rest % H;
    int b = rest / H;

    const Tin* img = in + (size_t)b * H * W;

    int xm = (x > 0) ? x - 1 : 0;
    int xp = (x < W - 1) ? x + 1 : x;
    int ym = (y > 0) ? y - 1 : 0;
    int yp = (y < H - 1) ? y + 1 : y;

    const Tin* r0 = img + (size_t)ym * W;
    const Tin* r1 = img + (size_t)y * W;
    const Tin* r2 = img + (size_t)yp * W;

    unsigned long long h = 0;
    h += 1ull << (((int)r0[xm]) * 8);
    h += 1ull << (((int)r0[x])  * 8);
    h += 1ull << (((int)r0[xp]) * 8);
    h += 1ull << (((int)r1[xm]) * 8);
    h += 1ull << (((int)r1[x])  * 8);
    h += 1ull << (((int)r1[xp]) * 8);
    h += 1ull << (((int)r2[xm]) * 8);
    h += 1ull << (((int)r2[x])  * 8);
    h += 1ull << (((int)r2[xp]) * 8);

    out[idx] = (Tout)argmax_hist8(h);
}

extern "C" void kernel_launch(void* const* d_in, const int* in_sizes, int n_in,
                              void* d_out, int out_size, void* d_ws, size_t ws_size,
                              hipStream_t stream) {
    const float* clusters = (const float*)d_in[0];
    // setup_inputs: B=8, H=768, W=768, footprint=3, num_bins=8, max_iter=8
    const int B = 8, H = 768, W = 768;
    const int total = B * H * W;  // == in_sizes[0] == 4718592
    (void)in_sizes; (void)n_in; (void)out_size; (void)ws_size;

    unsigned char* bufA = (unsigned char*)d_ws;
    unsigned char* bufB = bufA + total;

    const int threads = 256;
    const int blocks = (total + threads - 1) / threads;

    // Iteration 0: f32 -> u8
    majority_iter_kernel<float, unsigned char>
        <<<blocks, threads, 0, stream>>>(clusters, bufA, H, W, total);

    // Iterations 1..6: u8 -> u8 ping-pong
    unsigned char* src = bufA;
    unsigned char* dst = bufB;
    for (int it = 1; it < 7; ++it) {
        majority_iter_kernel<unsigned char, unsigned char>
            <<<blocks, threads, 0, stream>>>(src, dst, H, W, total);
        unsigned char* t = src; src = dst; dst = t;
    }

    // Iteration 7: u8 -> f32 into d_out
    majority_iter_kernel<unsigned char, float>
        <<<blocks, threads, 0, stream>>>(src, (float*)d_out, H, W, total);
}

// Round 2
// 57.729 us; speedup vs baseline: 2.5907x; 2.5907x over previous
//
#include <hip/hip_runtime.h>

// 3x3 majority filter, replicate padding, 8 bins, ties -> smallest label.
// 8 unconditional iterations (idempotent at fixed point == early-stop).
//
// Per-thread 8x2 tile. Packed-byte histograms: one u64, byte per bin,
// counts scaled by 8 so the low 3 bits of each byte carry a tie-break tag
// (7 - bin). Separable: column hists built once, window hist slides with
// one add + one sub. Argmax = byte-max of (count*8 | 7-bin).

static constexpr int W = 768, H = 768, B = 8;
static constexpr int P = 8;   // pixels per thread along x
static constexpr int R = 2;   // rows per thread
static constexpr unsigned long long TAG = 0x0001020304050607ull;

__device__ __forceinline__ unsigned int bmax(unsigned int a, unsigned int b) {
    return a > b ? a : b;
}

template <typename Tin>
__device__ __forceinline__ void load_row(const Tin* row, int x0, int lab[P + 2]) {
    if constexpr (sizeof(Tin) == 1) {
        unsigned long long mid =
            *reinterpret_cast<const unsigned long long*>((const unsigned char*)row + x0);
#pragma unroll
        for (int i = 0; i < 8; ++i) lab[i + 1] = (int)((mid >> (8 * i)) & 7u);
        lab[0] = (int)row[x0 > 0 ? x0 - 1 : 0];
        lab[9] = (int)row[x0 + P < W ? x0 + P : W - 1];
    } else {
        const float* frow = (const float*)row;
        float4 a = *reinterpret_cast<const float4*>(frow + x0);
        float4 c = *reinterpret_cast<const float4*>(frow + x0 + 4);
        lab[1] = (int)a.x; lab[2] = (int)a.y; lab[3] = (int)a.z; lab[4] = (int)a.w;
        lab[5] = (int)c.x; lab[6] = (int)c.y; lab[7] = (int)c.z; lab[8] = (int)c.w;
        lab[0] = (int)frow[x0 > 0 ? x0 - 1 : 0];
        lab[9] = (int)frow[x0 + P < W ? x0 + P : W - 1];
    }
}

template <typename Tin, typename Tout>
__global__ __launch_bounds__(256) void majority_kernel(
    const Tin* __restrict__ in, Tout* __restrict__ out) {
    int tid = blockIdx.x * 256 + threadIdx.x;
    int xg = tid % (W / P);
    int t2 = tid / (W / P);
    int yg = t2 % (H / R);
    int b  = t2 / (H / R);
    int x0 = xg * P, y0 = yg * R;

    const Tin* img = in + (size_t)b * H * W;
    Tout* oimg = out + (size_t)b * H * W;

    // Load R+2 input rows (clamped), 10 labels each.
    int lab[R + 2][P + 2];
#pragma unroll
    for (int r = 0; r < R + 2; ++r) {
        int yy = y0 + r - 1;
        yy = yy < 0 ? 0 : (yy >= H ? H - 1 : yy);
        load_row(img + (size_t)yy * W, x0, lab[r]);
    }

#pragma unroll
    for (int r = 0; r < R; ++r) {
        // Column histograms: byte per bin, count scaled by 8.
        unsigned long long ch[P + 2];
#pragma unroll
        for (int i = 0; i < P + 2; ++i)
            ch[i] = (8ull << (lab[r][i] * 8)) + (8ull << (lab[r + 1][i] * 8))
                  + (8ull << (lab[r + 2][i] * 8));

        unsigned long long s = ch[0] + ch[1] + ch[2];
        unsigned int labels[P];
#pragma unroll
        for (int j = 0; j < P; ++j) {
            unsigned long long hh = s + TAG;
            unsigned int lo = (unsigned int)hh;
            unsigned int hi = (unsigned int)(hh >> 32);
            unsigned int m = bmax(
                bmax(bmax(lo & 255u, (lo >> 8) & 255u),
                     bmax((lo >> 16) & 255u, lo >> 24)),
                bmax(bmax(hi & 255u, (hi >> 8) & 255u),
                     bmax((hi >> 16) & 255u, hi >> 24)));
            labels[j] = (m & 7u) ^ 7u;
            if (j < P - 1) s += ch[j + 3] - ch[j];
        }

        if constexpr (sizeof(Tout) == 1) {
            unsigned long long packed = 0;
#pragma unroll
            for (int j = 0; j < P; ++j)
                packed |= (unsigned long long)labels[j] << (8 * j);
            *reinterpret_cast<unsigned long long*>(
                (unsigned char*)oimg + (size_t)(y0 + r) * W + x0) = packed;
        } else {
            float* orow = (float*)oimg + (size_t)(y0 + r) * W + x0;
            *reinterpret_cast<float4*>(orow) =
                make_float4((float)labels[0], (float)labels[1],
                            (float)labels[2], (float)labels[3]);
            *reinterpret_cast<float4*>(orow + 4) =
                make_float4((float)labels[4], (float)labels[5],
                            (float)labels[6], (float)labels[7]);
        }
    }
}

extern "C" void kernel_launch(void* const* d_in, const int* in_sizes, int n_in,
                              void* d_out, int out_size, void* d_ws, size_t ws_size,
                              hipStream_t stream) {
    const float* clusters = (const float*)d_in[0];
    (void)in_sizes; (void)n_in; (void)out_size; (void)ws_size;

    const int total = B * H * W;
    unsigned char* bufA = (unsigned char*)d_ws;
    unsigned char* bufB = bufA + total;

    const int threads = 256;
    const int nthreads = B * (H / R) * (W / P);   // 294912
    const int blocks = nthreads / threads;        // 1152

    // Iteration 0: f32 -> u8
    majority_kernel<float, unsigned char>
        <<<blocks, threads, 0, stream>>>(clusters, bufA);

    // Iterations 1..6: u8 -> u8 ping-pong
    unsigned char* src = bufA;
    unsigned char* dst = bufB;
    for (int it = 1; it < 7; ++it) {
        majority_kernel<unsigned char, unsigned char>
            <<<blocks, threads, 0, stream>>>(src, dst);
        unsigned char* t = src; src = dst; dst = t;
    }

    // Iteration 7: u8 -> f32 into d_out
    majority_kernel<unsigned char, float>
        <<<blocks, threads, 0, stream>>>(src, (float*)d_out);
}